// Round 9
// baseline (629.393 us; speedup 1.0000x reference)
//
#include <hip/hip_runtime.h>
#include <type_traits>

#define N 4096
#define TILE 96            // output tile per block
#define HALO 16            // halo for 16 fused steps
#define SDIM 128           // staged rows/cols = TILE + 2*HALO
#define NSTRIP 16          // row strips per block
#define GH 8               // rows per strip (register-resident)
#define NSTEPS 16          // stencil iterations fused per pass
#define NB 43              // ceil(4096/96)

// Diffuse/AO shading for 4 pixels.
__device__ inline float4 shade(float4 v, float4 h, float4 n0, float4 n1, float4 n2) {
    const float SC = 0x1p-64f;   // undo 32 deferred 0.25 factors
    const float L0 = 0.7053f, L1 = -0.7053f, L2 = 0.7053f;
    float4 o;
    {
        float ao = 1.0f - fminf(fmaxf((v.x * SC - h.x) * 4.0f, 0.0f), 1.0f);
        float d1 = fmaxf(n0.x * L0 + n1.x * L1 + n2.x * L2, 0.0f);
        o.x = (d1 * 0.3f + 0.7f) * ao;
    }
    {
        float ao = 1.0f - fminf(fmaxf((v.y * SC - h.y) * 4.0f, 0.0f), 1.0f);
        float d1 = fmaxf(n0.y * L0 + n1.y * L1 + n2.y * L2, 0.0f);
        o.y = (d1 * 0.3f + 0.7f) * ao;
    }
    {
        float ao = 1.0f - fminf(fmaxf((v.z * SC - h.z) * 4.0f, 0.0f), 1.0f);
        float d1 = fmaxf(n0.z * L0 + n1.z * L1 + n2.z * L2, 0.0f);
        o.z = (d1 * 0.3f + 0.7f) * ao;
    }
    {
        float ao = 1.0f - fminf(fmaxf((v.w * SC - h.w) * 4.0f, 0.0f), 1.0f);
        float d1 = fmaxf(n0.w * L0 + n1.w * L1 + n2.w * L2, 0.0f);
        o.w = (d1 * 0.3f + 0.7f) * ao;
    }
    return o;
}

// 16 fused cross-stencil iterations. Thread (g=tid/16, l=tid%16) owns rows
// r0=8g..r0+7 at cols 8l..8l+7 (two float4 registers per row, held across all
// steps). Horizontal neighbors: register shifts + 2 shfl per row-step (lane
// crossings land on staging-edge cols -> inside garbage trapezoid).
// Vertical strip boundaries exchanged through double-buffered LDS, ONE
// barrier per step. Deferred 0.25 scaling; 2^-64 applied in final epilogue.
template <int FUSE>
__global__ __launch_bounds__(256, 4) void stencil16(const float* __restrict__ src,
                                                    float* __restrict__ dst,
                                                    const float* __restrict__ xin,
                                                    const float* __restrict__ nrm) {
    __shared__ float bnd[2][2][NSTRIP][SDIM];   // [buf][first/last][strip][col] = 32 KB
    const int bx = blockIdx.x, by = blockIdx.y;
    const int gi0 = by * TILE - HALO;
    const int gj0 = bx * TILE - HALO;
    const int tid = (int)threadIdx.x;
    const int g   = tid >> 4;          // strip 0..15
    const int l   = tid & 15;          // 8-col lane 0..15
    const int jc  = 8 * l;             // local col of first element
    const int r0  = 8 * g;             // first owned row
    const bool edge = (bx == 0) | (by == 0) | (bx == NB - 1) | (by == NB - 1);

    float4 ra[GH], rb[GH];             // two float4 per owned row

    // ---- stage strip into registers ----
    if (!edge) {
        const float* base = src + (size_t)(gi0 + r0) * N + (gj0 + jc);
#pragma unroll
        for (int k = 0; k < GH; ++k) {
            ra[k] = *(const float4*)(base + (size_t)k * N);
            rb[k] = *(const float4*)(base + (size_t)k * N + 4);
        }
    } else {
        auto ld4 = [&](int r, int c0) -> float4 {
            int gr = gi0 + r;
            gr = gr < 0 ? 0 : (gr > N - 1 ? N - 1 : gr);
            const int gc = gj0 + c0;
            if (gc >= 0 && gc + 3 <= N - 1)
                return *(const float4*)(src + (size_t)gr * N + gc);
            const float* row = src + (size_t)gr * N;
            return make_float4(row[min(max(gc + 0, 0), N - 1)],
                               row[min(max(gc + 1, 0), N - 1)],
                               row[min(max(gc + 2, 0), N - 1)],
                               row[min(max(gc + 3, 0), N - 1)]);
        };
#pragma unroll
        for (int k = 0; k < GH; ++k) {
            ra[k] = ld4(r0 + k, jc);
            rb[k] = ld4(r0 + k, jc + 4);
        }
    }

    const int gc0 = gj0 + jc;
    const bool lcl = edge && (gc0 == 0);           // a.x is global col 0
    const bool rcl = edge && (gc0 + 7 == N - 1);   // b.w is global col N-1

    // initial boundary publish -> buf 0
    *(float4*)&bnd[0][0][g][jc]     = ra[0];
    *(float4*)&bnd[0][0][g][jc + 4] = rb[0];
    *(float4*)&bnd[0][1][g][jc]     = ra[GH - 1];
    *(float4*)&bnd[0][1][g][jc + 4] = rb[GH - 1];
    __syncthreads();

    const int gm = (g == 0) ? 0 : g - 1;               // halo sources (clamped;
    const int gp = (g == NSTRIP - 1) ? NSTRIP - 1 : g + 1; // clamped cases never consumed)

    auto run = [&](auto EC) {
#pragma unroll 1
        for (int p = 0; p < NSTEPS; ++p) {
            const int s = p + 1;                       // valid rows/cols [s, SDIM-s)
            const int cbuf = p & 1;
            float4 ua = *(const float4*)&bnd[cbuf][1][gm][jc];
            float4 ub = *(const float4*)&bnd[cbuf][1][gm][jc + 4];
            float4 da = *(const float4*)&bnd[cbuf][0][gp][jc];
            float4 db = *(const float4*)&bnd[cbuf][0][gp][jc + 4];
            float4 pa = ua, pb = ub;                   // prev row (pre-update)
#pragma unroll
            for (int k = 0; k < GH; ++k) {
                const int r = r0 + k;
                const float4 ca = ra[k], cb = rb[k];
                const float4 na = (k < GH - 1) ? ra[k + 1] : da;
                const float4 nb2 = (k < GH - 1) ? rb[k + 1] : db;
                if (r >= s && r < SDIM - s) {
                    float lft = __shfl_up(cb.w, 1);    // col jc-1 (lane crossing -> edge garbage, OK)
                    float rgt = __shfl_down(ca.x, 1);  // col jc+8
                    float4 upa = pa, upb = pb, dna = na, dnb = nb2;
                    if constexpr (decltype(EC)::value) {
                        const int gr = gi0 + r;
                        if (gr == 0)     { upa = ca; upb = cb; }   // replicate pad = self
                        if (gr == N - 1) { dna = ca; dnb = cb; }
                        if (lcl) lft = ca.x;
                        if (rcl) rgt = cb.w;
                    }
                    float4 oa, ob;
                    oa.x = (upa.x + dna.x) + (lft  + ca.y);
                    oa.y = (upa.y + dna.y) + (ca.x + ca.z);
                    oa.z = (upa.z + dna.z) + (ca.y + ca.w);
                    oa.w = (upa.w + dna.w) + (ca.z + cb.x);
                    ob.x = (upb.x + dnb.x) + (ca.w + cb.y);
                    ob.y = (upb.y + dnb.y) + (cb.x + cb.z);
                    ob.z = (upb.z + dnb.z) + (cb.y + cb.w);
                    ob.w = (upb.w + dnb.w) + (cb.z + rgt);
                    ra[k] = oa; rb[k] = ob;
                }
                pa = ca; pb = cb;
            }
            // publish new boundary rows -> other buffer; single barrier per step
            const int nbuf = (p + 1) & 1;
            *(float4*)&bnd[nbuf][0][g][jc]     = ra[0];
            *(float4*)&bnd[nbuf][0][g][jc + 4] = rb[0];
            *(float4*)&bnd[nbuf][1][g][jc]     = ra[GH - 1];
            *(float4*)&bnd[nbuf][1][g][jc + 4] = rb[GH - 1];
            __syncthreads();
        }
    };
    if (edge) run(std::true_type{});
    else      run(std::false_type{});

    // ---- store interior [HALO, SDIM-HALO)^2 straight from registers ----
    if (l >= HALO / 8 && l < (SDIM - HALO) / 8) {      // lanes 2..13
#pragma unroll
        for (int k = 0; k < GH; ++k) {
            const int r = r0 + k;
            if (r < HALO || r >= SDIM - HALO) continue;
            const int gr = gi0 + r;
            if (edge && gr >= N) continue;
            const size_t base = (size_t)gr * N + gc0;
            const bool ok_a = !edge || (gc0 + 3 <= N - 1);
            const bool ok_b = !edge || (gc0 + 7 <= N - 1);
            if constexpr (FUSE) {
                if (ok_a) {
                    const float4 h  = *(const float4*)(xin + base);
                    const float4 n0 = *(const float4*)(nrm + base);
                    const float4 n1 = *(const float4*)(nrm + (size_t)N * N + base);
                    const float4 n2 = *(const float4*)(nrm + 2 * (size_t)N * N + base);
                    *(float4*)(dst + base) = shade(ra[k], h, n0, n1, n2);
                }
                if (ok_b) {
                    const float4 h  = *(const float4*)(xin + base + 4);
                    const float4 n0 = *(const float4*)(nrm + base + 4);
                    const float4 n1 = *(const float4*)(nrm + (size_t)N * N + base + 4);
                    const float4 n2 = *(const float4*)(nrm + 2 * (size_t)N * N + base + 4);
                    *(float4*)(dst + base + 4) = shade(rb[k], h, n0, n1, n2);
                }
            } else {
                if (ok_a) *(float4*)(dst + base)     = ra[k];
                if (ok_b) *(float4*)(dst + base + 4) = rb[k];
            }
        }
    }
}

extern "C" void kernel_launch(void* const* d_in, const int* in_sizes, int n_in,
                              void* d_out, int out_size, void* d_ws, size_t ws_size,
                              hipStream_t stream) {
    const float* x       = (const float*)d_in[0];
    const float* normals = (const float*)d_in[1];
    float* out = (float*)d_out;
    float* ws  = (float*)d_ws;

    dim3 grid(NB, NB);
    dim3 block(256);

    // 32 iterations = 2 passes x 16 fused steps
    stencil16<0><<<grid, block, 0, stream>>>(x,  ws,  nullptr, nullptr);
    // final pass: 16 steps + fused AO/diffuse epilogue
    stencil16<1><<<grid, block, 0, stream>>>(ws, out, x, normals);
}

// Round 11
// 254.269 us; speedup vs baseline: 2.4753x; 2.4753x over previous
//
#include <hip/hip_runtime.h>
#include <type_traits>

#define N 4096
#define TILE 96            // output tile per block
#define HALO 16            // halo for 16 fused steps
#define SDIM 128           // staged rows/cols = TILE + 2*HALO
#define NSTRIP 16          // row strips per block
#define GH 8               // rows per strip (register-resident)
#define NSTEPS 16          // stencil iterations fused per pass
#define NB 43              // ceil(4096/96)
#define SPAD 132           // bnd col stride (132 % 32 = 4 -> bank phase rotates per strip)

// DPP lane shifts within 16-lane rows. AMD semantics: row_shr:N -> dest[i]=src[i-N];
// row_shl:N -> dest[i]=src[i+N]. Our column groups are exactly 16 aligned lanes, so
// DPP row boundaries == group boundaries; boundary lanes keep their own value (old),
// which lands only on staging cols 0/127 inside the never-consumed garbage trapezoid.
__device__ __forceinline__ float dpp_prev(float x) {   // lane i <- lane i-1 (row_shr:1)
    int r = __builtin_amdgcn_update_dpp(__float_as_int(x), __float_as_int(x),
                                        0x111, 0xf, 0xf, false);
    return __int_as_float(r);
}
__device__ __forceinline__ float dpp_next(float x) {   // lane i <- lane i+1 (row_shl:1)
    int r = __builtin_amdgcn_update_dpp(__float_as_int(x), __float_as_int(x),
                                        0x101, 0xf, 0xf, false);
    return __int_as_float(r);
}

// Diffuse/AO shading for 4 pixels.
__device__ __forceinline__ float4 shade(float4 v, float4 h, float4 n0, float4 n1, float4 n2) {
    const float SC = 0x1p-64f;   // undo 32 deferred 0.25 factors
    const float L0 = 0.7053f, L1 = -0.7053f, L2 = 0.7053f;
    float4 o;
    {
        float ao = 1.0f - fminf(fmaxf((v.x * SC - h.x) * 4.0f, 0.0f), 1.0f);
        float d1 = fmaxf(n0.x * L0 + n1.x * L1 + n2.x * L2, 0.0f);
        o.x = (d1 * 0.3f + 0.7f) * ao;
    }
    {
        float ao = 1.0f - fminf(fmaxf((v.y * SC - h.y) * 4.0f, 0.0f), 1.0f);
        float d1 = fmaxf(n0.y * L0 + n1.y * L1 + n2.y * L2, 0.0f);
        o.y = (d1 * 0.3f + 0.7f) * ao;
    }
    {
        float ao = 1.0f - fminf(fmaxf((v.z * SC - h.z) * 4.0f, 0.0f), 1.0f);
        float d1 = fmaxf(n0.z * L0 + n1.z * L1 + n2.z * L2, 0.0f);
        o.z = (d1 * 0.3f + 0.7f) * ao;
    }
    {
        float ao = 1.0f - fminf(fmaxf((v.w * SC - h.w) * 4.0f, 0.0f), 1.0f);
        float d1 = fmaxf(n0.w * L0 + n1.w * L1 + n2.w * L2, 0.0f);
        o.w = (d1 * 0.3f + 0.7f) * ao;
    }
    return o;
}

// 16 fused cross-stencil iterations. Thread (g=tid/16, l=tid%16) owns rows
// r0=8g..r0+7 at cols 8l..8l+7 (two float4 regs per row, held across steps).
// Horizontal neighbors: in-register + DPP row_shr/shl (no LDS). Vertical strip
// boundaries via double-buffered padded LDS, one barrier per step.
// Deferred 0.25 scaling; 2^-64 applied once in the final epilogue.
template <int FUSE>
__global__ __launch_bounds__(256, 2) void stencil16(const float* __restrict__ src,
                                                    float* __restrict__ dst,
                                                    const float* __restrict__ xin,
                                                    const float* __restrict__ nrm) {
    __shared__ float bnd[2][2][NSTRIP][SPAD];   // [buf][first/last][strip][col]; 33.8 KB
    const int bx = blockIdx.x, by = blockIdx.y;
    const int gi0 = by * TILE - HALO;
    const int gj0 = bx * TILE - HALO;
    const int tid = (int)threadIdx.x;
    const int g   = tid >> 4;          // strip 0..15
    const int l   = tid & 15;          // 8-col lane 0..15
    const int jc  = 8 * l;             // local col of first element
    const int r0  = 8 * g;             // first owned row
    const bool edge = (bx == 0) | (by == 0) | (bx == NB - 1) | (by == NB - 1);

    float4 ra[GH], rb[GH];             // two float4 per owned row

    // ---- stage strip into registers ----
    if (!edge) {
        const float* base = src + (size_t)(gi0 + r0) * N + (gj0 + jc);
#pragma unroll
        for (int k = 0; k < GH; ++k) {
            ra[k] = *(const float4*)(base + (size_t)k * N);
            rb[k] = *(const float4*)(base + (size_t)k * N + 4);
        }
    } else {
        auto ld4 = [&](int r, int c0) -> float4 {
            int gr = gi0 + r;
            gr = gr < 0 ? 0 : (gr > N - 1 ? N - 1 : gr);
            const int gc = gj0 + c0;
            if (gc >= 0 && gc + 3 <= N - 1)
                return *(const float4*)(src + (size_t)gr * N + gc);
            const float* row = src + (size_t)gr * N;
            return make_float4(row[min(max(gc + 0, 0), N - 1)],
                               row[min(max(gc + 1, 0), N - 1)],
                               row[min(max(gc + 2, 0), N - 1)],
                               row[min(max(gc + 3, 0), N - 1)]);
        };
#pragma unroll
        for (int k = 0; k < GH; ++k) {
            ra[k] = ld4(r0 + k, jc);
            rb[k] = ld4(r0 + k, jc + 4);
        }
    }

    const int gc0 = gj0 + jc;
    const bool lcl = edge && (gc0 == 0);           // a.x is global col 0
    const bool rcl = edge && (gc0 + 7 == N - 1);   // b.w is global col N-1

    // initial boundary publish -> buf 0
    *(float4*)&bnd[0][0][g][jc]     = ra[0];
    *(float4*)&bnd[0][0][g][jc + 4] = rb[0];
    *(float4*)&bnd[0][1][g][jc]     = ra[GH - 1];
    *(float4*)&bnd[0][1][g][jc + 4] = rb[GH - 1];
    __syncthreads();

    const int gm = (g == 0) ? 0 : g - 1;                    // clamped cases feed only
    const int gp = (g == NSTRIP - 1) ? NSTRIP - 1 : g + 1;  // never-consumed rows 0/127

    auto run = [&](auto EC) {
#pragma unroll 1
        for (int p = 0; p < NSTEPS; ++p) {
            const int s = p + 1;                       // valid rows/cols [s, SDIM-s)
            const int cbuf = p & 1;
            float4 ua = *(const float4*)&bnd[cbuf][1][gm][jc];
            float4 ub = *(const float4*)&bnd[cbuf][1][gm][jc + 4];
            float4 da = *(const float4*)&bnd[cbuf][0][gp][jc];
            float4 db = *(const float4*)&bnd[cbuf][0][gp][jc + 4];
            float4 pa = ua, pb = ub;                   // prev row (pre-update)
#pragma unroll
            for (int k = 0; k < GH; ++k) {
                const int r = r0 + k;
                const float4 ca = ra[k], cb = rb[k];
                const float4 na  = (k < GH - 1) ? ra[k + 1] : da;
                const float4 nb2 = (k < GH - 1) ? rb[k + 1] : db;
                if (r >= s && r < SDIM - s) {          // uniform per 16-lane group
                    float lft = dpp_prev(cb.w);        // lane i-1's cb.w = col jc-1
                    float rgt = dpp_next(ca.x);        // lane i+1's ca.x = col jc+8
                    float4 upa = pa, upb = pb, dna = na, dnb = nb2;
                    if constexpr (decltype(EC)::value) {
                        const int gr = gi0 + r;
                        if (gr == 0)     { upa = ca; upb = cb; }   // pad replicate = self
                        if (gr == N - 1) { dna = ca; dnb = cb; }
                        if (lcl) lft = ca.x;
                        if (rcl) rgt = cb.w;
                    }
                    float4 oa, ob;
                    oa.x = (upa.x + dna.x) + (lft  + ca.y);
                    oa.y = (upa.y + dna.y) + (ca.x + ca.z);
                    oa.z = (upa.z + dna.z) + (ca.y + ca.w);
                    oa.w = (upa.w + dna.w) + (ca.z + cb.x);
                    ob.x = (upb.x + dnb.x) + (ca.w + cb.y);
                    ob.y = (upb.y + dnb.y) + (cb.x + cb.z);
                    ob.z = (upb.z + dnb.z) + (cb.y + cb.w);
                    ob.w = (upb.w + dnb.w) + (cb.z + rgt);
                    ra[k] = oa; rb[k] = ob;
                }
                pa = ca; pb = cb;
            }
            // publish new boundary rows -> other buffer; single barrier per step
            const int nbuf = cbuf ^ 1;
            *(float4*)&bnd[nbuf][0][g][jc]     = ra[0];
            *(float4*)&bnd[nbuf][0][g][jc + 4] = rb[0];
            *(float4*)&bnd[nbuf][1][g][jc]     = ra[GH - 1];
            *(float4*)&bnd[nbuf][1][g][jc + 4] = rb[GH - 1];
            __syncthreads();
        }
    };
    if (edge) run(std::true_type{});
    else      run(std::false_type{});

    // ---- store interior [HALO, SDIM-HALO)^2 straight from registers ----
    if (l >= HALO / 8 && l < (SDIM - HALO) / 8) {      // lanes 2..13
#pragma unroll
        for (int k = 0; k < GH; ++k) {
            const int r = r0 + k;
            if (r < HALO || r >= SDIM - HALO) continue;
            const int gr = gi0 + r;
            if (edge && gr >= N) continue;
            const size_t base = (size_t)gr * N + gc0;
            const bool ok_a = !edge || (gc0 + 3 <= N - 1);
            const bool ok_b = !edge || (gc0 + 7 <= N - 1);
            if constexpr (FUSE) {
                if (ok_a) {
                    const float4 h  = *(const float4*)(xin + base);
                    const float4 n0 = *(const float4*)(nrm + base);
                    const float4 n1 = *(const float4*)(nrm + (size_t)N * N + base);
                    const float4 n2 = *(const float4*)(nrm + 2 * (size_t)N * N + base);
                    *(float4*)(dst + base) = shade(ra[k], h, n0, n1, n2);
                }
                if (ok_b) {
                    const float4 h  = *(const float4*)(xin + base + 4);
                    const float4 n0 = *(const float4*)(nrm + base + 4);
                    const float4 n1 = *(const float4*)(nrm + (size_t)N * N + base + 4);
                    const float4 n2 = *(const float4*)(nrm + 2 * (size_t)N * N + base + 4);
                    *(float4*)(dst + base + 4) = shade(rb[k], h, n0, n1, n2);
                }
            } else {
                if (ok_a) *(float4*)(dst + base)     = ra[k];
                if (ok_b) *(float4*)(dst + base + 4) = rb[k];
            }
        }
    }
}

extern "C" void kernel_launch(void* const* d_in, const int* in_sizes, int n_in,
                              void* d_out, int out_size, void* d_ws, size_t ws_size,
                              hipStream_t stream) {
    const float* x       = (const float*)d_in[0];
    const float* normals = (const float*)d_in[1];
    float* out = (float*)d_out;
    float* ws  = (float*)d_ws;

    dim3 grid(NB, NB);
    dim3 block(256);

    // 32 iterations = 2 passes x 16 fused steps
    stencil16<0><<<grid, block, 0, stream>>>(x,  ws,  nullptr, nullptr);
    // final pass: 16 steps + fused AO/diffuse epilogue
    stencil16<1><<<grid, block, 0, stream>>>(ws, out, x, normals);
}